// Round 11
// baseline (227.878 us; speedup 1.0000x reference)
//
#include <hip/hip_runtime.h>

// img (3,512,512) f32, theta (64,) f32 -> out (64,3,512,512) f32
typedef float f4 __attribute__((ext_vector_type(4)));

constexpr int Hh = 512;
constexpr int Ww = 512;
constexpr int Nn = 64;
constexpr int HW = Hh * Ww;
constexpr int TS   = 16;   // output tile side
constexpr int ROWS = 26;   // bbox rows: floor-span 22 + 3 margin + 1
constexpr int COLS = 32;   // bbox cols 29 padded to pow2: swizzle bijective by construction

// Kernel 1: per-image cos/sin into workspace (ws re-poisoned every launch).
__global__ void precompute_cs(const float* __restrict__ theta,
                              float* __restrict__ cs) {
    int t = threadIdx.x;
    if (t < Nn) {
        float th = theta[t];
        cs[2 * t]     = cosf(th);
        cs[2 * t + 1] = sinf(th);
    }
}

// XOR swizzle: COLS=32 is a power of 2, so lc^m stays in [0,32) for any m<=31
// -> bijective per row, no overflow-collision class (round-6 lesson).
// &7 spreads 8 consecutive staged rows across all 8 LDS bank groups.
__device__ __forceinline__ int swz(int lr, int lc) {
    return lr * COLS + (lc ^ (lr & 7));
}

__global__ __launch_bounds__(256, 8) void rot_bilinear_lds16(
        const float* __restrict__ img,
        const float* __restrict__ cs,
        float* __restrict__ out)
{
    __shared__ f4 lds[ROWS * COLS];   // 13,312 B -> 8 blocks/CU (wave-capped), 100% occ

    const int n   = blockIdx.y;
    const int tix = blockIdx.x & 31;  // 32 tiles per row
    const int tiy = blockIdx.x >> 5;
    const int i0  = tiy * TS;
    const int j0  = tix * TS;

    const float c = cs[2 * n];
    const float s = cs[2 * n + 1];
    // ix = A + c*j - s*i ; iy = B + s*j + c*i  (exact linear map)
    const float A = 255.5f * (1.0f - c + s);
    const float B = 255.5f * (1.0f - s - c);

    // Source bbox from the 4 tile corners (linear -> extremes at corners).
    const float j0f = (float)j0, j1f = (float)(j0 + TS - 1);
    const float i0f = (float)i0, i1f = (float)(i0 + TS - 1);
    const float x00 = fmaf(c, j0f, fmaf(-s, i0f, A));
    const float x01 = fmaf(c, j1f, fmaf(-s, i0f, A));
    const float x10 = fmaf(c, j0f, fmaf(-s, i1f, A));
    const float x11 = fmaf(c, j1f, fmaf(-s, i1f, A));
    const float y00 = fmaf(s, j0f, fmaf(c, i0f, B));
    const float y01 = fmaf(s, j1f, fmaf(c, i0f, B));
    const float y10 = fmaf(s, j0f, fmaf(c, i1f, B));
    const float y11 = fmaf(s, j1f, fmaf(c, i1f, B));
    const float minx = fminf(fminf(x00, x01), fminf(x10, x11));
    const float maxx = fmaxf(fmaxf(x00, x01), fmaxf(x10, x11));
    const float miny = fminf(fminf(y00, y01), fminf(y10, y11));
    const float maxy = fmaxf(fmaxf(y00, y01), fmaxf(y10, y11));

    const int cmin = (int)floorf(minx) - 1;   // margin: floor-1 below, +2 above
    const int cmax = (int)floorf(maxx) + 2;
    const int rmin = (int)floorf(miny) - 1;
    const int rmax = (int)floorf(maxy) + 2;
    const int c0s = min(max(cmin, 0), 511);
    const int c1s = min(max(cmax, 0), 511);
    const int r0s = min(max(rmin, 0), 511);
    const int r1s = min(max(rmax, 0), 511);
    const int c0a = c0s & ~3;                 // float4-aligned col base
    const int width = c1s - c0a + 1;          // <= 29
    const int R     = r1s - r0s + 1;          // <= 26
    // Block-uniform: no corner of any px in this tile can be invalid or need clamping.
    const bool interior = (cmin >= 0) & (rmin >= 0) & (cmax <= 511) & (rmax <= 511);

    // ---- stage bbox: one row per thread-row, float4 chunks (single pass, no loop) ----
    // c0a+cA: both multiples of 4 and c0a+cA <= c1s <= 511 => <= 508 => +3 <= 511 (no OOB).
    const int tid = threadIdx.x;
    const int ty = tid >> 3;                  // 0..31 staged row (R<=26 used)
    const int cA = (tid & 7) << 2;            // 0,4,...,28 chunk col
    if (ty < R && cA < width) {
        const float* p = img + (r0s + ty) * Ww + c0a + cA;
        const f4 a0 = *(const f4*)p;
        const f4 a1 = *(const f4*)(p + HW);
        const f4 a2 = *(const f4*)(p + 2 * HW);
        #pragma unroll
        for (int e = 0; e < 4; ++e) {
            f4 v;
            v.x = a0[e]; v.y = a1[e]; v.z = a2[e]; v.w = 0.0f;
            lds[swz(ty, cA + e)] = v;
        }
    }
    __syncthreads();

    // ---- gather: 1 px/thread; wave = 4 rows x 16 consecutive cols
    // (same-row lanes sweep all 8 bank groups -> 2 lanes/group = conflict-free) ----
    const int row = tid >> 4;                 // 0..15
    const int col = tid & 15;                 // 0..15
    const int gi  = i0 + row;
    const int gj  = j0 + col;
    const float fi = (float)gi, fj = (float)gj;

    const float ix = fmaf(c, fj, fmaf(-s, fi, A));
    const float iy = fmaf(s, fj, fmaf(c, fi, B));

    f4 res;

    if (interior) {
        const float x0f = floorf(ix), y0f = floorf(iy);
        const float wx = ix - x0f,  wy = iy - y0f;
        const int xi = (int)x0f - c0a;        // x0f >= 1 when interior
        const int yi = (int)y0f - r0s;
        const float u0 = 1.0f - wx, v0 = 1.0f - wy;
        const float w00 = u0 * v0, w01 = wx * v0, w10 = u0 * wy, w11 = wx * wy;
        const int m0 = yi & 7, m1 = (yi + 1) & 7;
        const int rb0 = yi * COLS, rb1 = rb0 + COLS;
        const f4 v00 = lds[rb0 + ( xi      ^ m0)];
        const f4 v01 = lds[rb0 + ((xi + 1) ^ m0)];
        const f4 v10 = lds[rb1 + ( xi      ^ m1)];
        const f4 v11 = lds[rb1 + ((xi + 1) ^ m1)];
        res = v00 * w00 + v01 * w01 + v10 * w10 + v11 * w11;   // v_pk_fma_f32
    } else {
        const float x0f = floorf(ix), y0f = floorf(iy);
        const float wx = ix - x0f,  wy = iy - y0f;
        const float x1f = x0f + 1.0f, y1f = y0f + 1.0f;

        const bool vx0 = (x0f >= 0.0f) && (x0f <= 511.0f);
        const bool vx1 = (x1f >= 0.0f) && (x1f <= 511.0f);
        const bool vy0 = (y0f >= 0.0f) && (y0f <= 511.0f);
        const bool vy1 = (y1f >= 0.0f) && (y1f <= 511.0f);

        // Clamped indices always land inside the staged bbox (x0f>=cmin, x0f+1<=cmax
        // => clamp(.,0,511) within [c0s..c1s]; same for y).
        const int xi0 = min(max((int)x0f,     0), 511) - c0a;
        const int xi1 = min(max((int)x0f + 1, 0), 511) - c0a;
        const int yi0 = min(max((int)y0f,     0), 511) - r0s;
        const int yi1 = min(max((int)y0f + 1, 0), 511) - r0s;

        float w00 = (1.0f - wx) * (1.0f - wy); if (!(vx0 && vy0)) w00 = 0.0f;
        float w01 = wx * (1.0f - wy);          if (!(vx1 && vy0)) w01 = 0.0f;
        float w10 = (1.0f - wx) * wy;          if (!(vx0 && vy1)) w10 = 0.0f;
        float w11 = wx * wy;                   if (!(vx1 && vy1)) w11 = 0.0f;

        const f4 v00 = lds[swz(yi0, xi0)];
        const f4 v01 = lds[swz(yi0, xi1)];
        const f4 v10 = lds[swz(yi1, xi0)];
        const f4 v11 = lds[swz(yi1, xi1)];
        res = v00 * w00 + v01 * w01 + v10 * w10 + v11 * w11;
    }

    // ---- stores: wave covers 4 rows x 16 cols -> 4 full 64B lines per instr ----
    const size_t base = (size_t)n * (size_t)(3 * HW) + (size_t)gi * Ww + gj;
    out[base]          = res.x;
    out[base + HW]     = res.y;
    out[base + 2 * HW] = res.z;
}

extern "C" void kernel_launch(void* const* d_in, const int* in_sizes, int n_in,
                              void* d_out, int out_size, void* d_ws, size_t ws_size,
                              hipStream_t stream) {
    const float* img   = (const float*)d_in[0];
    const float* theta = (const float*)d_in[1];
    float*       out   = (float*)d_out;
    float*       cs    = (float*)d_ws;   // 512 B

    precompute_cs<<<1, 64, 0, stream>>>(theta, cs);

    dim3 grid((Hh / TS) * (Ww / TS), Nn);   // (1024, 64)
    rot_bilinear_lds16<<<grid, 256, 0, stream>>>(img, cs, out);
}